// Round 1
// baseline (145.052 us; speedup 1.0000x reference)
//
#include <hip/hip_runtime.h>
#include <math.h>

#define BATCH  512
#define NROWS  256
#define NVECS  8
#define VSIZE  128
#define DIM    1024   // NVECS*VSIZE
#define NCOMBO 256

// ---------------------------------------------------------------------------
// Phase-decoupled fused kernel.
// Tile = 8 b x 8 r = 64 pairs/block, 256 threads (4 waves), grid 64x32.
//
// Phase 1 (dot): same proven machinery as the 145us kernel (coalesced W tile
//   -> padded LDS, Q rows in VGPRs, 3-var xor butterfly), but the per-r chain
//   now ENDS at a 2-lane predicated write of the wave-uniform cos-sims into a
//   2 KB LDS buffer. No readlane broadcasts, no expand, no stores on the
//   dependency chain.
// Phase 2 (expand/store): 16 INDEPENDENT iterations per wave. Broadcast
//   ds_read_b128 of the 8 cos-sims (each wave reads only what it wrote -> no
//   barrier), ~27 VALU, one coalesced 1KB/wave float4 store. Pure streaming;
//   compiler can pipeline stores instead of hiding them behind shuffle chains.
// ---------------------------------------------------------------------------
__global__ __launch_bounds__(256) void fused_kernel(
    const float* __restrict__ q, const float* __restrict__ w,
    float* __restrict__ out) {
  __shared__ __align__(16) float Ws[8 * 1056];   // 33 KB: 8 rows, 8x(128+4)
  __shared__ __align__(16) float Cs[8 * 64];     // 2 KB: [b'][r*8+n]
  const int t    = threadIdx.x;
  const int wv   = t >> 6, lane = t & 63;
  const int bs   = blockIdx.x * 8, rs = blockIdx.y * 8;
  const int n    = lane >> 3, c = lane & 7;
  const int koff = n * VSIZE + c * 16;
  const int b0   = bs + 2 * wv;

  // stage W tile (8 x 1024 floats): consecutive threads -> consecutive 16B
  #pragma unroll
  for (int i = 0; i < 8; ++i) {
    int f = i * 256 + t;        // float4 index 0..2047
    int g = f << 2;             // element index
    int row = g >> 10, e = g & 1023;
    float4 v = *(const float4*)(w + (size_t)(rs + row) * DIM + e);
    *(float4*)(Ws + row * 1056 + (e >> 7) * 132 + (e & 127)) = v;
  }

  // Q rows -> registers; inline sub-vector inverse norms via butterfly.
  float4 qa[4], qb[4];
  float qs0 = 0.f, qs1 = 0.f;
  {
    const float* Q0 = q + (size_t)b0 * DIM + koff;
    #pragma unroll
    for (int j = 0; j < 4; ++j) {
      qa[j] = *(const float4*)(Q0 + 4 * j);
      qb[j] = *(const float4*)(Q0 + DIM + 4 * j);
      qs0 = fmaf(qa[j].x, qa[j].x, qs0); qs0 = fmaf(qa[j].y, qa[j].y, qs0);
      qs0 = fmaf(qa[j].z, qa[j].z, qs0); qs0 = fmaf(qa[j].w, qa[j].w, qs0);
      qs1 = fmaf(qb[j].x, qb[j].x, qs1); qs1 = fmaf(qb[j].y, qb[j].y, qs1);
      qs1 = fmaf(qb[j].z, qb[j].z, qs1); qs1 = fmaf(qb[j].w, qb[j].w, qs1);
    }
  }
  #pragma unroll
  for (int m = 1; m <= 4; m <<= 1) {
    qs0 += __shfl_xor(qs0, m, 64);
    qs1 += __shfl_xor(qs1, m, 64);
  }
  const float iq0 = 1.0f / fmaxf(sqrtf(qs0), 1e-8f);
  const float iq1 = 1.0f / fmaxf(sqrtf(qs1), 1e-8f);

  __syncthreads();

  // ---- Phase 1: dots + norms -> Cs (LDS) -------------------------------
  const float* Wb = Ws + n * 132 + c * 16;
  #pragma unroll 2
  for (int r = 0; r < 8; ++r) {
    const float* Wr = Wb + r * 1056;
    float s0 = 0.f, s1 = 0.f, wss = 0.f;
    #pragma unroll
    for (int j = 0; j < 4; ++j) {
      float4 w4 = *(const float4*)(Wr + 4 * j);
      s0 = fmaf(qa[j].x, w4.x, s0); s0 = fmaf(qa[j].y, w4.y, s0);
      s0 = fmaf(qa[j].z, w4.z, s0); s0 = fmaf(qa[j].w, w4.w, s0);
      s1 = fmaf(qb[j].x, w4.x, s1); s1 = fmaf(qb[j].y, w4.y, s1);
      s1 = fmaf(qb[j].z, w4.z, s1); s1 = fmaf(qb[j].w, w4.w, s1);
      wss = fmaf(w4.x, w4.x, wss); wss = fmaf(w4.y, w4.y, wss);
      wss = fmaf(w4.z, w4.z, wss); wss = fmaf(w4.w, w4.w, wss);
    }
    #pragma unroll
    for (int m = 1; m <= 4; m <<= 1) {
      s0  += __shfl_xor(s0, m, 64);
      s1  += __shfl_xor(s1, m, 64);
      wss += __shfl_xor(wss, m, 64);
    }
    const float iw  = 1.0f / fmaxf(sqrtf(wss), 1e-8f);
    const float cs0 = fmaxf(s0 * iq0 * iw, 0.f);
    const float cs1 = fmaxf(s1 * iq1 * iw, 0.f);
    // park the wave-uniform results: lane 8n writes cs0, lane 8n+1 writes cs1
    // (2-way bank aliasing between the two groups -> free per m136)
    float csv = (c == 0) ? cs0 : cs1;
    if (c < 2) Cs[(2 * wv + c) * 64 + r * 8 + n] = csv;
  }

  // ---- Phase 2: expand + stream stores ---------------------------------
  // No barrier: each wave reads only the Cs rows (b' = 2wv, 2wv+1) that it
  // wrote itself; in-wave LDS ordering is handled by lgkmcnt.
  const bool m2 = lane & 1,  m3 = lane & 2,  m4 = lane & 4;
  const bool m5 = lane & 8,  m6 = lane & 16, m7 = lane & 32;
  float* outL = out + lane * 4;
  #pragma unroll 4
  for (int pi = 0; pi < 16; ++pi) {
    const int p = wv * 16 + pi;           // p>>3 = b' in {2wv,2wv+1}, p&7 = r
    float4 va = *(const float4*)(Cs + p * 8);      // broadcast read: cs[0..3]
    float4 vb = *(const float4*)(Cs + p * 8 + 4);  // broadcast read: cs[4..7]
    float t2 = m2 ? 1.f - va.z : va.z;
    float t3 = m3 ? 1.f - va.w : va.w;
    float t4 = m4 ? 1.f - vb.x : vb.x;
    float t5 = m5 ? 1.f - vb.y : vb.y;
    float t6 = m6 ? 1.f - vb.z : vb.z;
    float t7 = m7 ? 1.f - vb.w : vb.w;
    float base = ((t2 * t3) * (t4 * t5)) * (t6 * t7);
    float c0 = va.x, c1 = va.y;
    float4 o;
    o.x = base * (c0 * c1);
    o.y = base * ((1.f - c0) * c1);
    o.z = base * (c0 * (1.f - c1));
    o.w = base * ((1.f - c0) * (1.f - c1));
    *(float4*)(outL +
        ((size_t)(bs + (p >> 3)) * NROWS + (rs + (p & 7))) * NCOMBO) = o;
  }
}

// ---------------------------------------------------------------------------
extern "C" void kernel_launch(void* const* d_in, const int* in_sizes, int n_in,
                              void* d_out, int out_size, void* d_ws, size_t ws_size,
                              hipStream_t stream) {
  const float* query  = (const float*)d_in[0];   // [512][1024]
  const float* weight = (const float*)d_in[1];   // [256][1024]
  float* out = (float*)d_out;                    // [512][256][256]
  (void)d_ws; (void)ws_size;

  hipLaunchKernelGGL(fused_kernel, dim3(64, 32), dim3(256), 0, stream,
                     query, weight, out);
}